// Round 14
// baseline (97.187 us; speedup 1.0000x reference)
//
#include <hip/hip_runtime.h>
#include <hip/hip_bf16.h>
#include <math.h>

// ---------------------------------------------------------------------------
// MMD loss:  mmd = 2*Sxx_upper/(n(n-1)) + 2*Syy_upper/(m(m-1)) - 2*Sxy/(n*m)
// k(a,b) = exp(-|a-b|^2 / 128)  (sigma^2 = D = 64), N = M = 8192, D = 64.
//
// Algebra: store A' = A * sqrt(log2e)/8 in bf16 and ns = -0.5*|a'|^2 (f32,
// NEGATED in prep). Then k = exp2( dot(a',b') + ns_a ) * exp2( ns_b ).
// MFMA C-operand = ns_a (16 regs, C/D row order); ey = exp2(ns_b) once per
// 32x32 tile; per element just exp2 + fma.
//
// Hard-won structure lessons (R0..R13):
//  - default __launch_bounds__(256) ONLY. (256,8) -> compiler spills (373us).
//  - NO single-address atomic finalize (~65us serialized tail, R1/R4).
//  - Guards ARE the register-pressure governor (R1: 108 VGPR, R10: 124).
//  - B panel in LDS, XOR-swizzle f(x)=x^(((x>>7)&7)<<4) BOTH sides (R7).
//  - TLP beyond ~2.5 blocks/CU neutral (R8); VGPR cliff at 128 (m69 class).
//  - R12: 32x32x16 MFMA + multiplicative ey fold: best total 95.8us.
//  - R13: 256-col panel REGRESSED (+7us main): A-traffic was never the
//    binder; conflicts 2.1M surfaced on the 32x32 read pattern.
//  - R14: LDS pipe is the largest per-CU floor (~10us, 537MB of reads, 4x
//    redundant across waves/chunks). Halve it: wave tile 64 rows = TWO
//    32x32 output tiles per B read (2-way vertical register blocking).
//    Block 512x128, 16KB panel, 2 chunks of 256 rows. Grid/decode/staging
//    identical to R12.
// ---------------------------------------------------------------------------

using short8  = __attribute__((ext_vector_type(8))) short;   // 8 bf16
using f32x4   = __attribute__((ext_vector_type(4))) float;
using f32x16  = __attribute__((ext_vector_type(16))) float;
using float4v = __attribute__((ext_vector_type(4))) float;

#define NROWS 8192
#define DDIM  64
// 1024 XY (dispatched first) + 2*544 sym-upper (512x128 blocks).
#define GRID_MAIN (1024 + 2 * 544)

// sqrt(log2(e)) / 8
#define PRESCALE 0.15014030109830622f

__device__ __forceinline__ float exp2_fast(float x) {
#if __has_builtin(__builtin_amdgcn_exp2f)
    return __builtin_amdgcn_exp2f(x);
#else
    return exp2f(x);
#endif
}

// ---------------------------------------------------------------------------
// Prep: normalize X, prescale, cast X/Y to bf16, compute ns = -0.5*|row'|^2
// (NEGATED: used directly as MFMA C-init / exp2 argument in main).
// 4 rows per wave, float4 loads. (R6-proven.)
// ---------------------------------------------------------------------------
__global__ __launch_bounds__(256) void mmd_prep(
    const float* __restrict__ z_seq, const float* __restrict__ pmean,
    const float* __restrict__ pstd, const float* __restrict__ z_prior,
    __hip_bfloat16* __restrict__ Xb, __hip_bfloat16* __restrict__ Yb,
    float* __restrict__ sxx, float* __restrict__ syy)
{
    const int tid  = threadIdx.x;
    const int lane = tid & 63;
    const int wid  = tid >> 6;
    const int w    = blockIdx.x * 4 + wid;       // wave id, 0..4095
    const int sub  = lane >> 4;                  // row within wave, 0..3
    const int row  = w * 4 + sub;                // 0..16383
    const int d0   = (lane & 15) * 4;            // dim offset, 0..60

    float4v v;
    __hip_bfloat16* dst;
    float* sdst;
    int r;
    if (row < NROWS) {
        r = row;
        float4v z  = *reinterpret_cast<const float4v*>(z_seq + (size_t)r * DDIM + d0);
        float4v pm = *reinterpret_cast<const float4v*>(pmean + d0);
        float4v ps = *reinterpret_cast<const float4v*>(pstd + d0);
#pragma unroll
        for (int k = 0; k < 4; ++k) v[k] = (z[k] - pm[k]) / ps[k];
        dst = Xb; sdst = sxx;
    } else {
        r = row - NROWS;
        v = *reinterpret_cast<const float4v*>(z_prior + (size_t)r * DDIM + d0);
        dst = Yb; sdst = syy;
    }

    ushort4 hb;
    float sq = 0.0f;
#pragma unroll
    for (int k = 0; k < 4; ++k) {
        __hip_bfloat16 b = __float2bfloat16(v[k] * PRESCALE);
        reinterpret_cast<__hip_bfloat16*>(&hb)[k] = b;
        float vb = __bfloat162float(b);
        sq += vb * vb;
    }
    *reinterpret_cast<ushort4*>(dst + (size_t)r * DDIM + d0) = hb;

    // reduce across the 16 lanes of this row-group (xor<16 stays in group)
#pragma unroll
    for (int off = 8; off; off >>= 1) sq += __shfl_xor(sq, off, 64);
    if ((lane & 15) == 0) sdst[r] = -0.5f * sq;   // NEGATED
}

// ---------------------------------------------------------------------------
// Main: compact 1-D grid of ACTIVE blocks only.
// Block tile 512(i) x 128(j): B panel (128x64 bf16 = 16KB) staged once,
// 2 A-chunks of 256 rows swept. 4 waves; per chunk each wave owns 64 rows
// as TWO 32x32 sub-tiles sharing each B read (v_mfma_f32_32x32x16_bf16).
//   bid <  1024 : XY block, bi = bid>>6 (0..15), bj = bid&63.
//   bid >= 1024 : t = bid-1024; sym mode = t&1 (0:XX, 1:YY);
//                 u = t>>1 in [0,544): bj = 4g+rem/(g+1), bi = rem%(g+1).
// 32x32 C/D layout: col = lane&31, row = (reg&3) + 8*(reg>>2) + 4*(lane>>5).
// A/B operand: row/col = lane&31, k = 8*(lane>>5) + elem(0..7).
// ---------------------------------------------------------------------------
__global__ __launch_bounds__(256) void mmd_main(
    const __hip_bfloat16* __restrict__ Xb, const __hip_bfloat16* __restrict__ Yb,
    const float* __restrict__ sxx, const float* __restrict__ syy,
    double* __restrict__ partials)
{
    __shared__ __align__(16) char Bs[16384];     // 128 cols x 128 B

    const int bid = blockIdx.x;

    int bi, bj;
    bool sym;
    const __hip_bfloat16* A;
    const __hip_bfloat16* Bp;
    const float* sa;
    const float* sb;

    if (bid < 1024) {                       // XY: heavy, uniform, FIRST
        sym = false;
        bi = bid >> 6; bj = bid & 63;
        A = Xb; Bp = Yb; sa = sxx; sb = syy;
    } else {                                // sym upper-triangle blocks
        sym = true;
        const int t = bid - 1024;
        const int u = t >> 1;
        int g = (int)((sqrtf((float)(2 * u + 1)) - 1.0f) * 0.5f);
        while (2 * (g + 1) * (g + 2) <= u) ++g;  // integer fixup of float sqrt
        while (2 * g * (g + 1) > u) --g;
        const int rem = u - 2 * g * (g + 1);     // 0 .. 4(g+1)-1
        const int q   = rem / (g + 1);           // 0..3
        bj = 4 * g + q;
        bi = rem - q * (g + 1);                  // 0..g  (jB >= iB guaranteed)
        if (t & 1) { A = Yb; Bp = Yb; sa = syy; sb = syy; }
        else       { A = Xb; Bp = Xb; sa = sxx; sb = sxx; }
    }

    const int tid  = threadIdx.x;
    const int lane = tid & 63;
    const int wid  = tid >> 6;
    const int l31  = lane & 31;
    const int h    = lane >> 5;                  // 0/1: k-half

    const int iBlock = bi * 512;
    const int jBlock = bj * 128;

    // ---- Stage B panel -> LDS, source pre-swizzled with f(x)=x^(((x>>7)&7)<<4)
    // so a swizzled read is conflict-free.  16 chunks of 1024B, 4 per wave.
    {
        const char* gB = (const char*)Bp + (size_t)jBlock * 128;
#pragma unroll
        for (int k = 0; k < 4; ++k) {
            const int c  = wid * 4 + k;
            const int x  = c * 1024 + lane * 16;
            const int gx = x ^ (((x >> 7) & 7) << 4);
            __builtin_amdgcn_global_load_lds(
                (const __attribute__((address_space(1))) void*)(gB + gx),
                (__attribute__((address_space(3))) void*)(Bs + c * 1024),
                16, 0, 0);
        }
    }

    // A-chunk 0 wave row origin (64 rows per wave); chunk 1 adds 256.
    int i0 = iBlock + wid * 64;

    // Two A sub-tiles (rows i0.. and i0+32..): fragments + C-init each.
    short8 a0f0, a0f1, a0f2, a0f3, a1f0, a1f1, a1f2, a1f3;
    f32x16 cin0, cin1;
    {
        const char* ar0 = (const char*)A + (size_t)(i0 + l31) * 128 + 16 * h;
        a0f0 = *reinterpret_cast<const short8*>(ar0);
        a0f1 = *reinterpret_cast<const short8*>(ar0 + 32);
        a0f2 = *reinterpret_cast<const short8*>(ar0 + 64);
        a0f3 = *reinterpret_cast<const short8*>(ar0 + 96);
        const char* ar1 = ar0 + 32 * 128;
        a1f0 = *reinterpret_cast<const short8*>(ar1);
        a1f1 = *reinterpret_cast<const short8*>(ar1 + 32);
        a1f2 = *reinterpret_cast<const short8*>(ar1 + 64);
        a1f3 = *reinterpret_cast<const short8*>(ar1 + 96);
        const float* sn0 = sa + i0 + 4 * h;
#pragma unroll
        for (int q = 0; q < 4; ++q) {
            f32x4 t0 = *reinterpret_cast<const f32x4*>(sn0 + 8 * q);
            f32x4 t1 = *reinterpret_cast<const f32x4*>(sn0 + 32 + 8 * q);
            cin0[4 * q + 0] = t0[0]; cin0[4 * q + 1] = t0[1];
            cin0[4 * q + 2] = t0[2]; cin0[4 * q + 3] = t0[3];
            cin1[4 * q + 0] = t1[0]; cin1[4 * q + 1] = t1[1];
            cin1[4 * q + 2] = t1[2]; cin1[4 * q + 3] = t1[3];
        }
    }

    // Negated column half-norms for this lane's 4 j-subtiles.
    float nsy4[4];
#pragma unroll
    for (int nt = 0; nt < 4; ++nt) nsy4[nt] = sb[jBlock + nt * 32 + l31];

    __syncthreads();   // staging complete (compiler drains vmcnt first)

    // Per-lane constant swizzle for reads: col&7 == l31&7 (col = 32nt+l31).
    const int swz = (l31 & 7) << 4;
    const int bo0 = (16 * h +  0) ^ swz;
    const int bo1 = (16 * h + 32) ^ swz;
    const int bo2 = (16 * h + 64) ^ swz;
    const int bo3 = (16 * h + 96) ^ swz;
    const char* lbbase = Bs + l31 * 128;

    // 4 accumulators break the serial add chain.
    float ls0 = 0.0f, ls1 = 0.0f, ls2 = 0.0f, ls3 = 0.0f;

    for (int c = 0; c < 2; ++c) {
#pragma unroll
        for (int nt = 0; nt < 4; ++nt) {
            const int jt = jBlock + nt * 32;
            if (sym && jt < i0) continue;        // both sub-tiles below diag

            const char* lp = lbbase + nt * 4096;
            short8 b0 = *reinterpret_cast<const short8*>(lp + bo0);
            short8 b1 = *reinterpret_cast<const short8*>(lp + bo1);
            short8 b2 = *reinterpret_cast<const short8*>(lp + bo2);
            short8 b3 = *reinterpret_cast<const short8*>(lp + bo3);

            const float ey = exp2_fast(nsy4[nt]);   // exp2(-s_b), per tile-col

            // ---- sub-tile 0: rows i0 .. i0+31 ----
            {
                f32x16 acc = __builtin_amdgcn_mfma_f32_32x32x16_bf16(a0f0, b0, cin0, 0, 0, 0);
                acc = __builtin_amdgcn_mfma_f32_32x32x16_bf16(a0f1, b1, acc, 0, 0, 0);
                acc = __builtin_amdgcn_mfma_f32_32x32x16_bf16(a0f2, b2, acc, 0, 0, 0);
                acc = __builtin_amdgcn_mfma_f32_32x32x16_bf16(a0f3, b3, acc, 0, 0, 0);

                if (sym && jt == i0) {
                    const int rb = 4 * h;
#pragma unroll
                    for (int r = 0; r < 16; ++r) {
                        const int rowr = rb + (r & 3) + 8 * (r >> 2);
                        float v = exp2_fast(acc[r]) * ey;
                        float m = (l31 > rowr) ? v : 0.0f;
                        if ((r & 3) == 0) ls0 += m;
                        else if ((r & 3) == 1) ls1 += m;
                        else if ((r & 3) == 2) ls2 += m;
                        else ls3 += m;
                    }
                } else {
#pragma unroll
                    for (int r = 0; r < 16; ++r) {
                        float e = exp2_fast(acc[r]);
                        if ((r & 3) == 0) ls0 = fmaf(e, ey, ls0);
                        else if ((r & 3) == 1) ls1 = fmaf(e, ey, ls1);
                        else if ((r & 3) == 2) ls2 = fmaf(e, ey, ls2);
                        else ls3 = fmaf(e, ey, ls3);
                    }
                }
            }

            // ---- sub-tile 1: rows i0+32 .. i0+63 ----
            if (!(sym && jt < i0 + 32)) {
                f32x16 acc = __builtin_amdgcn_mfma_f32_32x32x16_bf16(a1f0, b0, cin1, 0, 0, 0);
                acc = __builtin_amdgcn_mfma_f32_32x32x16_bf16(a1f1, b1, acc, 0, 0, 0);
                acc = __builtin_amdgcn_mfma_f32_32x32x16_bf16(a1f2, b2, acc, 0, 0, 0);
                acc = __builtin_amdgcn_mfma_f32_32x32x16_bf16(a1f3, b3, acc, 0, 0, 0);

                if (sym && jt == i0 + 32) {
                    const int rb = 4 * h;
#pragma unroll
                    for (int r = 0; r < 16; ++r) {
                        const int rowr = rb + (r & 3) + 8 * (r >> 2);
                        float v = exp2_fast(acc[r]) * ey;
                        float m = (l31 > rowr) ? v : 0.0f;
                        if ((r & 3) == 0) ls0 += m;
                        else if ((r & 3) == 1) ls1 += m;
                        else if ((r & 3) == 2) ls2 += m;
                        else ls3 += m;
                    }
                } else {
#pragma unroll
                    for (int r = 0; r < 16; ++r) {
                        float e = exp2_fast(acc[r]);
                        if ((r & 3) == 0) ls0 = fmaf(e, ey, ls0);
                        else if ((r & 3) == 1) ls1 = fmaf(e, ey, ls1);
                        else if ((r & 3) == 2) ls2 = fmaf(e, ey, ls2);
                        else ls3 = fmaf(e, ey, ls3);
                    }
                }
            }
        }

        // Load chunk 1's A fragments + C-init (rows += 256).
        if (c == 0) {
            const int i0n = i0 + 256;
            if (sym && jBlock + 96 < i0n) break;    // all later tiles empty
            const char* ar0 = (const char*)A + (size_t)(i0n + l31) * 128 + 16 * h;
            a0f0 = *reinterpret_cast<const short8*>(ar0);
            a0f1 = *reinterpret_cast<const short8*>(ar0 + 32);
            a0f2 = *reinterpret_cast<const short8*>(ar0 + 64);
            a0f3 = *reinterpret_cast<const short8*>(ar0 + 96);
            const char* ar1 = ar0 + 32 * 128;
            a1f0 = *reinterpret_cast<const short8*>(ar1);
            a1f1 = *reinterpret_cast<const short8*>(ar1 + 32);
            a1f2 = *reinterpret_cast<const short8*>(ar1 + 64);
            a1f3 = *reinterpret_cast<const short8*>(ar1 + 96);
            const float* sn0 = sa + i0n + 4 * h;
#pragma unroll
            for (int q = 0; q < 4; ++q) {
                f32x4 t0 = *reinterpret_cast<const f32x4*>(sn0 + 8 * q);
                f32x4 t1 = *reinterpret_cast<const f32x4*>(sn0 + 32 + 8 * q);
                cin0[4 * q + 0] = t0[0]; cin0[4 * q + 1] = t0[1];
                cin0[4 * q + 2] = t0[2]; cin0[4 * q + 3] = t0[3];
                cin1[4 * q + 0] = t1[0]; cin1[4 * q + 1] = t1[1];
                cin1[4 * q + 2] = t1[2]; cin1[4 * q + 3] = t1[3];
            }
            i0 = i0n;
        }
    }

    float lsum = (ls0 + ls1) + (ls2 + ls3);

    // wave reduce
#pragma unroll
    for (int off = 32; off; off >>= 1) lsum += __shfl_xor(lsum, off, 64);

    __shared__ float ws4[4];
    if (lane == 0) ws4[wid] = lsum;
    __syncthreads();
    if (tid == 0) {
        double tot = (double)ws4[0] + (double)ws4[1] + (double)ws4[2] + (double)ws4[3];
        partials[bid] = tot;
    }
}

// ---------------------------------------------------------------------------
// Finalize: reduce GRID_MAIN block partials with per-mode coefficients.
// bid < 1024 -> XY (negative coeff); else sym (x2 folds sum_{i!=j}).
// ---------------------------------------------------------------------------
__global__ __launch_bounds__(256) void mmd_final(
    const double* __restrict__ partials, float* __restrict__ out)
{
    const int tid = threadIdx.x;
    const double cs = 2.0 / (8192.0 * 8191.0);       // sym modes
    const double cx = -2.0 / (8192.0 * 8192.0);      // XY

    double s = 0.0;
    for (int idx = tid; idx < GRID_MAIN; idx += 256) {
        double c = (idx < 1024) ? cx : cs;
        s += partials[idx] * c;
    }
#pragma unroll
    for (int off = 32; off; off >>= 1) s += __shfl_xor(s, off, 64);

    __shared__ double wsum[4];
    const int lane = tid & 63, wid = tid >> 6;
    if (lane == 0) wsum[wid] = s;
    __syncthreads();
    if (tid == 0) {
        double mmd = wsum[0] + wsum[1] + wsum[2] + wsum[3];
        out[0] = (float)(mmd > 0.0 ? mmd : 0.0);
    }
}

// ---------------------------------------------------------------------------
extern "C" void kernel_launch(void* const* d_in, const int* in_sizes, int n_in,
                              void* d_out, int out_size, void* d_ws, size_t ws_size,
                              hipStream_t stream) {
    const float* z_seq   = (const float*)d_in[0];   // [16,512,64]
    const float* pmean   = (const float*)d_in[1];   // [64]
    const float* pstd    = (const float*)d_in[2];   // [64]
    const float* z_prior = (const float*)d_in[3];   // [8192,64]
    float* out = (float*)d_out;

    char* ws = (char*)d_ws;
    __hip_bfloat16* Xb = (__hip_bfloat16*)(ws);                    // 1 MB
    __hip_bfloat16* Yb = (__hip_bfloat16*)(ws + (1u << 20));       // 1 MB
    float* sxx = (float*)(ws + (2u << 20));                        // 32 KB
    float* syy = (float*)(ws + (2u << 20) + 32768);                // 32 KB
    double* partials = (double*)(ws + (2u << 20) + 65536);         // ~17 KB

    mmd_prep<<<dim3(1024), dim3(256), 0, stream>>>(
        z_seq, pmean, pstd, z_prior, Xb, Yb, sxx, syy);
    mmd_main<<<dim3(GRID_MAIN), dim3(256), 0, stream>>>(
        Xb, Yb, sxx, syy, partials);
    mmd_final<<<dim3(1), dim3(256), 0, stream>>>(partials, out);
}

// Round 16
// 95.736 us; speedup vs baseline: 1.0152x; 1.0152x over previous
//
#include <hip/hip_runtime.h>
#include <hip/hip_bf16.h>
#include <math.h>

// ---------------------------------------------------------------------------
// MMD loss:  mmd = 2*Sxx_upper/(n(n-1)) + 2*Syy_upper/(m(m-1)) - 2*Sxy/(n*m)
// k(a,b) = exp(-|a-b|^2 / 128)  (sigma^2 = D = 64), N = M = 8192, D = 64.
//
// Algebra: store A' = A * sqrt(log2e)/8 in bf16 and ns = -0.5*|a'|^2 (f32,
// NEGATED in prep). Then k = exp2( dot(a',b') + ns_a ) * exp2( ns_b ).
// MFMA C-operand = ns_a (16 regs, C/D row order); ey = exp2(ns_b) hoisted to
// the block prologue; per element just exp2 + fma.
//
// Hard-won structure lessons (R0..R14):
//  - default __launch_bounds__(256) ONLY. (256,8) -> compiler spills (373us).
//  - NO single-address atomic finalize (~65us serialized tail, R1/R4).
//  - Guards ARE the register-pressure governor (R1: 108 VGPR, R10: 124).
//  - B panel in LDS, XOR-swizzle f(x)=x^(((x>>7)&7)<<4) BOTH sides (R7).
//  - Refuted as binders: TLP/occupancy (R8), 1-deep ILP (R11), panel width
//    (R13), LDS read volume + intra-wave MFMA||VALU overlap (R14).
//  - R12 champion: 32x32x16 MFMA + multiplicative ey fold, 95.8us total.
//  - R15: consolidation. (a) sym blocks dispatched heavy-first (bi asc,
//    bj DESC) so work is monotone non-increasing across the grid ->
//    minimal drain tail; (b) ey exp2 hoisted out of the nt loop.
//    (R15 bench was an infra failure; resubmitted unchanged.)
// ---------------------------------------------------------------------------

using short8  = __attribute__((ext_vector_type(8))) short;   // 8 bf16
using f32x4   = __attribute__((ext_vector_type(4))) float;
using f32x16  = __attribute__((ext_vector_type(16))) float;
using float4v = __attribute__((ext_vector_type(4))) float;

#define NROWS 8192
#define DDIM  64
// 1024 XY (dispatched first) + 2*544 sym-upper (512x128 blocks).
#define GRID_MAIN (1024 + 2 * 544)

// sqrt(log2(e)) / 8
#define PRESCALE 0.15014030109830622f

__device__ __forceinline__ float exp2_fast(float x) {
#if __has_builtin(__builtin_amdgcn_exp2f)
    return __builtin_amdgcn_exp2f(x);
#else
    return exp2f(x);
#endif
}

// ---------------------------------------------------------------------------
// Prep: normalize X, prescale, cast X/Y to bf16, compute ns = -0.5*|row'|^2
// (NEGATED: used directly as MFMA C-init / exp2 argument in main).
// 4 rows per wave, float4 loads. (R6-proven.)
// ---------------------------------------------------------------------------
__global__ __launch_bounds__(256) void mmd_prep(
    const float* __restrict__ z_seq, const float* __restrict__ pmean,
    const float* __restrict__ pstd, const float* __restrict__ z_prior,
    __hip_bfloat16* __restrict__ Xb, __hip_bfloat16* __restrict__ Yb,
    float* __restrict__ sxx, float* __restrict__ syy)
{
    const int tid  = threadIdx.x;
    const int lane = tid & 63;
    const int wid  = tid >> 6;
    const int w    = blockIdx.x * 4 + wid;       // wave id, 0..4095
    const int sub  = lane >> 4;                  // row within wave, 0..3
    const int row  = w * 4 + sub;                // 0..16383
    const int d0   = (lane & 15) * 4;            // dim offset, 0..60

    float4v v;
    __hip_bfloat16* dst;
    float* sdst;
    int r;
    if (row < NROWS) {
        r = row;
        float4v z  = *reinterpret_cast<const float4v*>(z_seq + (size_t)r * DDIM + d0);
        float4v pm = *reinterpret_cast<const float4v*>(pmean + d0);
        float4v ps = *reinterpret_cast<const float4v*>(pstd + d0);
#pragma unroll
        for (int k = 0; k < 4; ++k) v[k] = (z[k] - pm[k]) / ps[k];
        dst = Xb; sdst = sxx;
    } else {
        r = row - NROWS;
        v = *reinterpret_cast<const float4v*>(z_prior + (size_t)r * DDIM + d0);
        dst = Yb; sdst = syy;
    }

    ushort4 hb;
    float sq = 0.0f;
#pragma unroll
    for (int k = 0; k < 4; ++k) {
        __hip_bfloat16 b = __float2bfloat16(v[k] * PRESCALE);
        reinterpret_cast<__hip_bfloat16*>(&hb)[k] = b;
        float vb = __bfloat162float(b);
        sq += vb * vb;
    }
    *reinterpret_cast<ushort4*>(dst + (size_t)r * DDIM + d0) = hb;

    // reduce across the 16 lanes of this row-group (xor<16 stays in group)
#pragma unroll
    for (int off = 8; off; off >>= 1) sq += __shfl_xor(sq, off, 64);
    if ((lane & 15) == 0) sdst[r] = -0.5f * sq;   // NEGATED
}

// ---------------------------------------------------------------------------
// Main: compact 1-D grid of ACTIVE blocks only.
// Block tile 512(i) x 128(j): B panel (128x64 bf16 = 16KB) staged once,
// 4 A-chunks of 128 rows swept. 4 waves; per chunk each wave owns 32 rows
// x 4 j-subtiles of 32x32 (v_mfma_f32_32x32x16_bf16, K=16 x4 = K64).
//   bid <  1024 : XY block, bi = bid>>6 (0..15), bj = bid&63.
//   bid >= 1024 : t = bid-1024; sym mode = t&1 (0:XX, 1:YY);
//                 u = t>>1 in [0,544): HEAVY-FIRST enumeration —
//                 bi ascending, bj DESCENDING from 63 to 4*bi.
//                 C(bi) = 66*bi - 2*bi^2; r = u - C(bi); bj = 63 - r.
// 32x32 C/D layout: col = lane&31, row = (reg&3) + 8*(reg>>2) + 4*(lane>>5).
// A/B operand: row/col = lane&31, k = 8*(lane>>5) + elem(0..7).
// ---------------------------------------------------------------------------
__global__ __launch_bounds__(256) void mmd_main(
    const __hip_bfloat16* __restrict__ Xb, const __hip_bfloat16* __restrict__ Yb,
    const float* __restrict__ sxx, const float* __restrict__ syy,
    double* __restrict__ partials)
{
    __shared__ __align__(16) char Bs[16384];     // 128 cols x 128 B

    const int bid = blockIdx.x;

    int bi, bj;
    bool sym;
    const __hip_bfloat16* A;
    const __hip_bfloat16* Bp;
    const float* sa;
    const float* sb;

    if (bid < 1024) {                       // XY: heavy, uniform, FIRST
        sym = false;
        bi = bid >> 6; bj = bid & 63;
        A = Xb; Bp = Yb; sa = sxx; sb = syy;
    } else {                                // sym upper blocks, heavy-first
        sym = true;
        const int t = bid - 1024;
        const int u = t >> 1;               // 0..543
        int b = (int)((33.0f - sqrtf(1089.0f - 2.0f * (float)u)) * 0.5f);
        if (b < 0) b = 0;
        if (b > 16) b = 16;                 // clamp seed; fixup loops finish
        while (66 * (b + 1) - 2 * (b + 1) * (b + 1) <= u) ++b;  // fixup
        while (66 * b - 2 * b * b > u) --b;
        bi = b;
        const int r = u - (66 * b - 2 * b * b);  // 0 .. 63-4bi
        bj = 63 - r;                             // descending: heavy first
        if (t & 1) { A = Yb; Bp = Yb; sa = syy; sb = syy; }
        else       { A = Xb; Bp = Xb; sa = sxx; sb = sxx; }
    }

    const int tid  = threadIdx.x;
    const int lane = tid & 63;
    const int wid  = tid >> 6;
    const int l31  = lane & 31;
    const int h    = lane >> 5;                  // 0/1: k-half

    const int iBlock = bi * 512;
    const int jBlock = bj * 128;

    // ---- Stage B panel -> LDS, source pre-swizzled with f(x)=x^(((x>>7)&7)<<4)
    // so a swizzled read is conflict-free.  16 chunks of 1024B, 4 per wave.
    {
        const char* gB = (const char*)Bp + (size_t)jBlock * 128;
#pragma unroll
        for (int k = 0; k < 4; ++k) {
            const int c  = wid * 4 + k;
            const int x  = c * 1024 + lane * 16;
            const int gx = x ^ (((x >> 7) & 7) << 4);
            __builtin_amdgcn_global_load_lds(
                (const __attribute__((address_space(1))) void*)(gB + gx),
                (__attribute__((address_space(3))) void*)(Bs + c * 1024),
                16, 0, 0);
        }
    }

    // A-chunk 0 wave row origin; chunk c adds 128.
    int i0 = iBlock + wid * 32;

    // A fragments (4 k-slices) + C-init (negated row half-norms in C/D
    // register order: reg r <- rows 8*(r>>2) + 4h + (r&3)).
    short8 af0, af1, af2, af3;
    f32x16 cin;
    {
        const char* arow = (const char*)A + (size_t)(i0 + l31) * 128 + 16 * h;
        af0 = *reinterpret_cast<const short8*>(arow);
        af1 = *reinterpret_cast<const short8*>(arow + 32);
        af2 = *reinterpret_cast<const short8*>(arow + 64);
        af3 = *reinterpret_cast<const short8*>(arow + 96);
        const float* sna = sa + i0 + 4 * h;
#pragma unroll
        for (int q = 0; q < 4; ++q) {
            f32x4 t = *reinterpret_cast<const f32x4*>(sna + 8 * q);
            cin[4 * q + 0] = t[0]; cin[4 * q + 1] = t[1];
            cin[4 * q + 2] = t[2]; cin[4 * q + 3] = t[3];
        }
    }

    // ey = exp2(-s_b) per j-subtile, computed ONCE per block (hoisted).
    float ey4[4];
#pragma unroll
    for (int nt = 0; nt < 4; ++nt)
        ey4[nt] = exp2_fast(sb[jBlock + nt * 32 + l31]);

    __syncthreads();   // staging complete (compiler drains vmcnt first)

    // Per-lane constant swizzle for reads: col&7 == l31&7 (col = 32nt+l31).
    const int swz = (l31 & 7) << 4;
    const int bo0 = (16 * h +  0) ^ swz;
    const int bo1 = (16 * h + 32) ^ swz;
    const int bo2 = (16 * h + 64) ^ swz;
    const int bo3 = (16 * h + 96) ^ swz;
    const char* lbbase = Bs + l31 * 128;

    // 4 accumulators break the serial add chain.
    float ls0 = 0.0f, ls1 = 0.0f, ls2 = 0.0f, ls3 = 0.0f;

    for (int c = 0; c < 4; ++c) {
#pragma unroll
        for (int nt = 0; nt < 4; ++nt) {
            const int jt = jBlock + nt * 32;
            if (sym && jt < i0) continue;        // tile strictly below diag

            const char* lp = lbbase + nt * 4096;
            short8 b0 = *reinterpret_cast<const short8*>(lp + bo0);
            short8 b1 = *reinterpret_cast<const short8*>(lp + bo1);
            short8 b2 = *reinterpret_cast<const short8*>(lp + bo2);
            short8 b3 = *reinterpret_cast<const short8*>(lp + bo3);

            f32x16 acc = __builtin_amdgcn_mfma_f32_32x32x16_bf16(af0, b0, cin, 0, 0, 0);
            acc = __builtin_amdgcn_mfma_f32_32x32x16_bf16(af1, b1, acc, 0, 0, 0);
            acc = __builtin_amdgcn_mfma_f32_32x32x16_bf16(af2, b2, acc, 0, 0, 0);
            acc = __builtin_amdgcn_mfma_f32_32x32x16_bf16(af3, b3, acc, 0, 0, 0);

            const float ey = ey4[nt];

            if (sym && jt == i0) {
                // diagonal tile: count only j > i; row_r = (r&3)+8*(r>>2)+4h
                const int rb = 4 * h;
#pragma unroll
                for (int r = 0; r < 16; ++r) {
                    const int rowr = rb + (r & 3) + 8 * (r >> 2);
                    float v = exp2_fast(acc[r]) * ey;
                    float m = (l31 > rowr) ? v : 0.0f;
                    if ((r & 3) == 0) ls0 += m;
                    else if ((r & 3) == 1) ls1 += m;
                    else if ((r & 3) == 2) ls2 += m;
                    else ls3 += m;
                }
            } else {
#pragma unroll
                for (int r = 0; r < 16; ++r) {
                    float e = exp2_fast(acc[r]);
                    if ((r & 3) == 0) ls0 = fmaf(e, ey, ls0);
                    else if ((r & 3) == 1) ls1 = fmaf(e, ey, ls1);
                    else if ((r & 3) == 2) ls2 = fmaf(e, ey, ls2);
                    else ls3 = fmaf(e, ey, ls3);
                }
            }
        }

        // Load next chunk's A fragments + C-init.
        if (c < 3) {
            const int i0n = i0 + 128;
            if (sym && jBlock + 96 < i0n) break;    // all later tiles empty
            const char* arow = (const char*)A + (size_t)(i0n + l31) * 128 + 16 * h;
            af0 = *reinterpret_cast<const short8*>(arow);
            af1 = *reinterpret_cast<const short8*>(arow + 32);
            af2 = *reinterpret_cast<const short8*>(arow + 64);
            af3 = *reinterpret_cast<const short8*>(arow + 96);
            const float* sna = sa + i0n + 4 * h;
#pragma unroll
            for (int q = 0; q < 4; ++q) {
                f32x4 t = *reinterpret_cast<const f32x4*>(sna + 8 * q);
                cin[4 * q + 0] = t[0]; cin[4 * q + 1] = t[1];
                cin[4 * q + 2] = t[2]; cin[4 * q + 3] = t[3];
            }
            i0 = i0n;
        }
    }

    float lsum = (ls0 + ls1) + (ls2 + ls3);

    // wave reduce
#pragma unroll
    for (int off = 32; off; off >>= 1) lsum += __shfl_xor(lsum, off, 64);

    __shared__ float ws4[4];
    if (lane == 0) ws4[wid] = lsum;
    __syncthreads();
    if (tid == 0) {
        double tot = (double)ws4[0] + (double)ws4[1] + (double)ws4[2] + (double)ws4[3];
        partials[bid] = tot;
    }
}

// ---------------------------------------------------------------------------
// Finalize: reduce GRID_MAIN block partials with per-mode coefficients.
// bid < 1024 -> XY (negative coeff); else sym (x2 folds sum_{i!=j}).
// ---------------------------------------------------------------------------
__global__ __launch_bounds__(256) void mmd_final(
    const double* __restrict__ partials, float* __restrict__ out)
{
    const int tid = threadIdx.x;
    const double cs = 2.0 / (8192.0 * 8191.0);       // sym modes
    const double cx = -2.0 / (8192.0 * 8192.0);      // XY

    double s = 0.0;
    for (int idx = tid; idx < GRID_MAIN; idx += 256) {
        double c = (idx < 1024) ? cx : cs;
        s += partials[idx] * c;
    }
#pragma unroll
    for (int off = 32; off; off >>= 1) s += __shfl_xor(s, off, 64);

    __shared__ double wsum[4];
    const int lane = tid & 63, wid = tid >> 6;
    if (lane == 0) wsum[wid] = s;
    __syncthreads();
    if (tid == 0) {
        double mmd = wsum[0] + wsum[1] + wsum[2] + wsum[3];
        out[0] = (float)(mmd > 0.0 ? mmd : 0.0);
    }
}

// ---------------------------------------------------------------------------
extern "C" void kernel_launch(void* const* d_in, const int* in_sizes, int n_in,
                              void* d_out, int out_size, void* d_ws, size_t ws_size,
                              hipStream_t stream) {
    const float* z_seq   = (const float*)d_in[0];   // [16,512,64]
    const float* pmean   = (const float*)d_in[1];   // [64]
    const float* pstd    = (const float*)d_in[2];   // [64]
    const float* z_prior = (const float*)d_in[3];   // [8192,64]
    float* out = (float*)d_out;

    char* ws = (char*)d_ws;
    __hip_bfloat16* Xb = (__hip_bfloat16*)(ws);                    // 1 MB
    __hip_bfloat16* Yb = (__hip_bfloat16*)(ws + (1u << 20));       // 1 MB
    float* sxx = (float*)(ws + (2u << 20));                        // 32 KB
    float* syy = (float*)(ws + (2u << 20) + 32768);                // 32 KB
    double* partials = (double*)(ws + (2u << 20) + 65536);         // ~17 KB

    mmd_prep<<<dim3(1024), dim3(256), 0, stream>>>(
        z_seq, pmean, pstd, z_prior, Xb, Yb, sxx, syy);
    mmd_main<<<dim3(GRID_MAIN), dim3(256), 0, stream>>>(
        Xb, Yb, sxx, syy, partials);
    mmd_final<<<dim3(1), dim3(256), 0, stream>>>(partials, out);
}